// Round 1
// baseline (201.007 us; speedup 1.0000x reference)
//
#include <hip/hip_runtime.h>
#include <math.h>

#define NN 8192
#define IN_F 128
#define OUT_F 64
#define PSTRIDE 68              // padded row stride (floats) -> 272B rows, 16B aligned
#define JSPLIT 8
#define BM 64
#define BK 64
#define JRANGE (NN / JSPLIT)    // 1024
#define NTILES (JRANGE / BK)    // 16

// K1: per node j compute Wh_j (64), s2_j = leakyrelu(Wh_j) . b[64:], E_j = exp(s2_j)
//     P[j][0..63] = E_j * Wh_j ; P[j][64] = E_j ; P[j][65..67] = 0 (pad)
__global__ __launch_bounds__(64) void k1_prep(const float* __restrict__ x,
                                              const float* __restrict__ W,
                                              const float* __restrict__ b,
                                              float* __restrict__ P) {
    const int row = blockIdx.x;
    const int f = threadIdx.x;           // 0..63
    __shared__ float xs[IN_F];
    xs[f]      = x[row * IN_F + f];
    xs[f + 64] = x[row * IN_F + f + 64];
    __syncthreads();
    float wh = 0.f;
    #pragma unroll 8
    for (int k = 0; k < IN_F; ++k)
        wh = fmaf(xs[k], W[k * OUT_F + f], wh);
    const float lr = wh >= 0.f ? wh : 0.2f * wh;
    float v = lr * b[OUT_F + f];
    #pragma unroll
    for (int off = 32; off > 0; off >>= 1)
        v += __shfl_xor(v, off, 64);     // all lanes hold s2
    const float E = expf(v);
    P[row * PSTRIDE + f] = E * wh;
    if (f == 0) P[row * PSTRIDE + 64] = E;
    if (f >= 1 && f <= 3) P[row * PSTRIDE + 64 + f] = 0.f;
}

// K2: masked GEMM partials. Block = 64 rows x 1024 j-range (one of 8 splits).
// Thread (cg=tid&15, rg=tid>>4): 4 rows (rg*4..+3) x 4 cols (cg*4..+3) + den.
__global__ __launch_bounds__(256, 4) void k2_gemm(const int* __restrict__ adj,
                                                  const float* __restrict__ P,
                                                  float* __restrict__ part) {
    const int i0 = blockIdx.x * BM;
    const int j0 = blockIdx.y * JRANGE;
    __shared__ __align__(16) float As[BM][PSTRIDE];
    __shared__ __align__(16) float Ps[BK][PSTRIDE];
    const int tid = threadIdx.x;
    const int cg = tid & 15;
    const int rg = tid >> 4;
    float acc[4][4] = {};
    float accd[4] = {};

    for (int t = 0; t < NTILES; ++t) {
        const int jt0 = j0 + t * BK;
        // stage adj tile (coalesced: 64 consecutive ints per wave-row)
        #pragma unroll
        for (int k = 0; k < 16; ++k) {
            const int e = tid + k * 256;
            const int r = e >> 6, j = e & 63;
            As[r][j] = adj[(i0 + r) * NN + jt0 + j] ? 1.f : 0.f;
        }
        // stage P tile as float4
        for (int q = tid; q < BK * (PSTRIDE / 4); q += 256) {
            const int jj = q / (PSTRIDE / 4);
            const int c4 = q - jj * (PSTRIDE / 4);
            *reinterpret_cast<float4*>(&Ps[jj][c4 * 4]) =
                *reinterpret_cast<const float4*>(&P[(jt0 + jj) * PSTRIDE + c4 * 4]);
        }
        __syncthreads();
        #pragma unroll 4
        for (int jj = 0; jj < BK; jj += 2) {
            const float4 p0 = *reinterpret_cast<const float4*>(&Ps[jj][cg * 4]);
            const float4 p1 = *reinterpret_cast<const float4*>(&Ps[jj + 1][cg * 4]);
            const float e0 = Ps[jj][64];
            const float e1 = Ps[jj + 1][64];
            #pragma unroll
            for (int t4 = 0; t4 < 4; ++t4) {
                const float2 a = *reinterpret_cast<const float2*>(&As[rg * 4 + t4][jj]);
                acc[t4][0] = fmaf(a.x, p0.x, acc[t4][0]);
                acc[t4][1] = fmaf(a.x, p0.y, acc[t4][1]);
                acc[t4][2] = fmaf(a.x, p0.z, acc[t4][2]);
                acc[t4][3] = fmaf(a.x, p0.w, acc[t4][3]);
                acc[t4][0] = fmaf(a.y, p1.x, acc[t4][0]);
                acc[t4][1] = fmaf(a.y, p1.y, acc[t4][1]);
                acc[t4][2] = fmaf(a.y, p1.z, acc[t4][2]);
                acc[t4][3] = fmaf(a.y, p1.w, acc[t4][3]);
                accd[t4] = fmaf(a.x, e0, accd[t4]);   // den (identical across cg; cg==0 writes)
                accd[t4] = fmaf(a.y, e1, accd[t4]);
            }
        }
        __syncthreads();
    }

    float* base = part + (size_t)blockIdx.y * NN * PSTRIDE;
    #pragma unroll
    for (int t4 = 0; t4 < 4; ++t4) {
        const int r = i0 + rg * 4 + t4;
        *reinterpret_cast<float4*>(&base[r * PSTRIDE + cg * 4]) =
            make_float4(acc[t4][0], acc[t4][1], acc[t4][2], acc[t4][3]);
        if (cg == 0) base[r * PSTRIDE + 64] = accd[t4];
    }
}

// K3: combine splits, out = elu(num/den)
__global__ __launch_bounds__(256) void k3_combine(const float* __restrict__ part,
                                                  float* __restrict__ out) {
    const int idx = blockIdx.x * 256 + threadIdx.x;
    const int i = idx >> 6;
    const int f = idx & 63;
    float num = 0.f, den = 0.f;
    #pragma unroll
    for (int s = 0; s < JSPLIT; ++s) {
        num += part[((size_t)s * NN + i) * PSTRIDE + f];
        den += part[((size_t)s * NN + i) * PSTRIDE + 64];
    }
    const float o = num / den;
    out[idx] = o > 0.f ? o : expm1f(o);
}

extern "C" void kernel_launch(void* const* d_in, const int* in_sizes, int n_in,
                              void* d_out, int out_size, void* d_ws, size_t ws_size,
                              hipStream_t stream) {
    const float* x   = (const float*)d_in[0];   // mole_out [8192,128]
    const int*   adj = (const int*)d_in[1];     // [8192,8192]
    const float* W   = (const float*)d_in[2];   // [128,64]
    const float* b   = (const float*)d_in[3];   // [128]
    float* out = (float*)d_out;

    float* P    = (float*)d_ws;                          // 8192*68*4   = 2.23 MB
    float* part = P + (size_t)NN * PSTRIDE;              // 8*8192*68*4 = 17.8 MB

    k1_prep<<<NN, 64, 0, stream>>>(x, W, b, P);
    k2_gemm<<<dim3(NN / BM, JSPLIT), 256, 0, stream>>>(adj, P, part);
    k3_combine<<<(NN * OUT_F) / 256, 256, 0, stream>>>(part, out);
}

// Round 2
// 82.118 us; speedup vs baseline: 2.4478x; 2.4478x over previous
//
#include <hip/hip_runtime.h>
#include <math.h>

#define NN 8192
#define IN_F 128
#define OUT_F 64
#define PBS 80                // Pb row stride (bf16 elements)
#define JS 8                  // K-splits
#define BM 128
#define BK 64
#define KRANGE (NN / JS)      // 1024
#define NTILE (KRANGE / BK)   // 16
#define PS_PART 65            // partial row stride (f32)

typedef __bf16 bf16x8 __attribute__((ext_vector_type(8)));
typedef float f32x4 __attribute__((ext_vector_type(4)));

// K1: per node, Wh (64 cols), s2 = leakyrelu(Wh).b[64:], E = exp(s2).
// Pb[row][0..63] = bf16(E*Wh), Pb[row][64] = bf16(E), Pb[row][65..79] = 0.
__global__ __launch_bounds__(64) void k1_prep(const float* __restrict__ x,
                                              const float* __restrict__ W,
                                              const float* __restrict__ b,
                                              __bf16* __restrict__ Pb) {
    const int row = blockIdx.x;
    const int f = threadIdx.x;           // 0..63
    __shared__ float xs[IN_F];
    xs[f]      = x[row * IN_F + f];
    xs[f + 64] = x[row * IN_F + f + 64];
    __syncthreads();
    float wh = 0.f;
    #pragma unroll 8
    for (int k = 0; k < IN_F; ++k)
        wh = fmaf(xs[k], W[k * OUT_F + f], wh);
    const float lr = wh >= 0.f ? wh : 0.2f * wh;
    float v = lr * b[OUT_F + f];
    #pragma unroll
    for (int off = 32; off > 0; off >>= 1)
        v += __shfl_xor(v, off, 64);     // all lanes: s2
    const float E = expf(v);
    Pb[row * PBS + f] = (__bf16)(E * wh);
    if (f == 0)            Pb[row * PBS + 64] = (__bf16)E;
    if (f >= 1 && f <= 15) Pb[row * PBS + 64 + f] = (__bf16)0.f;
}

// KT: transpose Pb[8192][80] -> Pt[80][8192] (bf16), coalesced both sides via LDS.
__global__ __launch_bounds__(256) void kT(const __bf16* __restrict__ Pb,
                                          __bf16* __restrict__ Pt) {
    const int k0 = blockIdx.x * 64;
    __shared__ __bf16 t[64][81];
    for (int idx = threadIdx.x; idx < 64 * 80; idx += 256) {
        const int r = idx / 80, c = idx - r * 80;
        t[r][c] = Pb[(k0 + r) * PBS + c];
    }
    __syncthreads();
    for (int idx = threadIdx.x; idx < 64 * 80; idx += 256) {
        const int c = idx >> 6, r = idx & 63;
        Pt[(size_t)c * NN + k0 + r] = t[r][c];
    }
}

__device__ __forceinline__ unsigned pk(int a, int b) {
    // pack two {0,1} ints as two bf16 (1.0f = 0x3F80)
    return (a > 0 ? 0x3F80u : 0u) | (b > 0 ? 0x3F800000u : 0u);
}

// K2: masked GEMM via bf16 MFMA. Block = 128 rows x K-range 1024 (one of 8 splits).
// 8 waves, wave w owns M-tile w (16 rows) x 5 N-tiles (80 cols: 64 num + den + pad).
__global__ __launch_bounds__(512, 4) void k2_mfma(const int* __restrict__ adj,
                                                  const __bf16* __restrict__ Pt,
                                                  float* __restrict__ part) {
    const int i0 = blockIdx.x * BM;
    const int kbase = blockIdx.y * KRANGE;
    __shared__ __align__(16) __bf16 As[BM][72];   // 72-pitch (144B): 2-way max on b128 reads
    __shared__ __align__(16) __bf16 Ps[80][72];
    const int tid = threadIdx.x;
    const int l = tid & 63, w = tid >> 6;
    const int lm = l & 15, lk8 = (l >> 4) << 3;

    f32x4 acc0{}, acc1{}, acc2{}, acc3{}, acc4{};

    // A staging: thread -> row ar, 16 ints starting at col ac (4 x dwordx4)
    const int ar = tid >> 2;
    const int ac = (tid & 3) << 4;

#define LOADA(t)                                                                   \
    {                                                                              \
        const int4* p = (const int4*)(adj + (size_t)(i0 + ar) * NN + kbase +       \
                                      (t) * BK + ac);                              \
        A0 = p[0]; A1 = p[1]; A2 = p[2]; A3 = p[3];                                \
    }

    int4 A0, A1, A2, A3;
    LOADA(0);

    for (int t = 0; t < NTILE; ++t) {
        const uint4 w0 = make_uint4(pk(A0.x, A0.y), pk(A0.z, A0.w),
                                    pk(A1.x, A1.y), pk(A1.z, A1.w));
        const uint4 w1 = make_uint4(pk(A2.x, A2.y), pk(A2.z, A2.w),
                                    pk(A3.x, A3.y), pk(A3.z, A3.w));
        if (t + 1 < NTILE) LOADA(t + 1);          // issue-early: in flight across MFMA
        __syncthreads();                          // all waves done reading LDS tile t-1
        *(uint4*)&As[ar][ac] = w0;
        *(uint4*)&As[ar][ac + 8] = w1;
        {   // stage Pt K-slice: 80 rows x 64 bf16 (L2-resident source)
            const int r = tid >> 3, c8 = (tid & 7) << 3;
            *(uint4*)&Ps[r][c8] =
                *(const uint4*)(Pt + (size_t)r * NN + kbase + t * BK + c8);
            if (tid < 128) {
                const int c2 = 512 + tid;
                const int r2 = c2 >> 3, c82 = (c2 & 7) << 3;
                *(uint4*)&Ps[r2][c82] =
                    *(const uint4*)(Pt + (size_t)r2 * NN + kbase + t * BK + c82);
            }
        }
        __syncthreads();
        #pragma unroll
        for (int ks = 0; ks < 2; ++ks) {
            const bf16x8 af = *(const bf16x8*)&As[w * 16 + lm][ks * 32 + lk8];
            const bf16x8 b0 = *(const bf16x8*)&Ps[lm][ks * 32 + lk8];
            const bf16x8 b1 = *(const bf16x8*)&Ps[16 + lm][ks * 32 + lk8];
            const bf16x8 b2 = *(const bf16x8*)&Ps[32 + lm][ks * 32 + lk8];
            const bf16x8 b3 = *(const bf16x8*)&Ps[48 + lm][ks * 32 + lk8];
            const bf16x8 b4 = *(const bf16x8*)&Ps[64 + lm][ks * 32 + lk8];
            acc0 = __builtin_amdgcn_mfma_f32_16x16x32_bf16(af, b0, acc0, 0, 0, 0);
            acc1 = __builtin_amdgcn_mfma_f32_16x16x32_bf16(af, b1, acc1, 0, 0, 0);
            acc2 = __builtin_amdgcn_mfma_f32_16x16x32_bf16(af, b2, acc2, 0, 0, 0);
            acc3 = __builtin_amdgcn_mfma_f32_16x16x32_bf16(af, b3, acc3, 0, 0, 0);
            acc4 = __builtin_amdgcn_mfma_f32_16x16x32_bf16(af, b4, acc4, 0, 0, 0);
        }
    }
#undef LOADA

    // epilogue: C/D layout col = lane&15, row = (lane>>4)*4 + reg
    float* base = part + (size_t)blockIdx.y * NN * PS_PART;
    const int row0 = i0 + w * 16 + (l >> 4) * 4;
    #pragma unroll
    for (int r = 0; r < 4; ++r) {
        base[(row0 + r) * PS_PART + lm]      = acc0[r];
        base[(row0 + r) * PS_PART + 16 + lm] = acc1[r];
        base[(row0 + r) * PS_PART + 32 + lm] = acc2[r];
        base[(row0 + r) * PS_PART + 48 + lm] = acc3[r];
        if (lm == 0) base[(row0 + r) * PS_PART + 64] = acc4[r];
    }
}

// K3: combine splits, out = elu(num/den)
__global__ __launch_bounds__(256) void k3_combine(const float* __restrict__ part,
                                                  float* __restrict__ out) {
    const int idx = blockIdx.x * 256 + threadIdx.x;
    const int i = idx >> 6;
    const int f = idx & 63;
    float num = 0.f, den = 0.f;
    #pragma unroll
    for (int s = 0; s < JS; ++s) {
        num += part[((size_t)s * NN + i) * PS_PART + f];
        den += part[((size_t)s * NN + i) * PS_PART + 64];
    }
    const float o = num / den;
    out[idx] = o > 0.f ? o : expm1f(o);
}

extern "C" void kernel_launch(void* const* d_in, const int* in_sizes, int n_in,
                              void* d_out, int out_size, void* d_ws, size_t ws_size,
                              hipStream_t stream) {
    const float* x   = (const float*)d_in[0];   // [8192,128]
    const int*   adj = (const int*)d_in[1];     // [8192,8192]
    const float* W   = (const float*)d_in[2];   // [128,64]
    const float* b   = (const float*)d_in[3];   // [128]
    float* out = (float*)d_out;

    __bf16* Pb  = (__bf16*)d_ws;                       // 8192*80*2  = 1.31 MB
    __bf16* Pt  = Pb + (size_t)NN * PBS;               // 80*8192*2  = 1.31 MB
    float*  part = (float*)(Pt + (size_t)PBS * NN);    // 8*8192*65*4 = 17.04 MB

    k1_prep<<<NN, 64, 0, stream>>>(x, W, b, Pb);
    kT<<<NN / 64, 256, 0, stream>>>(Pb, Pt);
    k2_mfma<<<dim3(NN / BM, JS), 512, 0, stream>>>(adj, Pt, part);
    k3_combine<<<(NN * OUT_F) / 256, 256, 0, stream>>>(part, out);
}